// Round 18
// baseline (545.685 us; speedup 1.0000x reference)
//
#include <hip/hip_runtime.h>

// SPModel_6846177870356: y = x@W^T + all2all permute. M=28160, N=K=2048.
// Inputs FP32 (harness-upcast fp16), output FP32.
// Round 18: flatmm-style B-DIRECT-FROM-L2 (AITER s01 pattern).
// R9..R17 invariant: MfmaUtil pinned 25-31% at 1 block/CU — barrier convoys
// with no co-resident block to overlap (m114). Fix occupancy, not schedule:
//  - B never touches LDS: per-wave 16B k-contiguous register loads from a
//    LINEAR f16 W copy (8MB, L2/L3-resident)
//  - LDS = A only, single-buffered 16KB -> 2 blocks/CU (launch_bounds(256,2))
//  - 128x128 tile, 4 waves (2x2) of 64x64, m97 2-barrier loop (no hand vmcnt)
//  - A staged via global_load_lds from pre-swizzled Xs (R9-verified), XOR
//    ds_read (T2, 0 conflicts), setprio (T5), XCD swizzle (T1), fused a2a.

typedef _Float16 f16;
typedef _Float16 f16x2 __attribute__((ext_vector_type(2)));
typedef _Float16 f16x8 __attribute__((ext_vector_type(8)));
typedef float    f32x4 __attribute__((ext_vector_type(4)));

#define GPTR(p) ((const __attribute__((address_space(1))) void*)(p))
#define LPTR(p) ((__attribute__((address_space(3))) void*)(p))

constexpr int Mdim = 28160;   // 8*44*80
constexpr int Ndim = 2048;
constexpr int Kdim = 2048;
constexpr int BM = 128, BN = 128, BK = 64;
constexpr int NWG = (Mdim / BM) * (Ndim / BN);  // 220*16 = 3520 (%8==0)
constexpr int NT  = Kdim / BK;                  // 32
constexpr size_t XS_ELEMS = (size_t)Mdim * Kdim;
constexpr size_t WS_ELEMS = (size_t)Ndim * Kdim;
constexpr size_t WS_NEED  = (XS_ELEMS + WS_ELEMS) * sizeof(f16);

__device__ __forceinline__ f16x8 pack8(const f32x4& lo, const f32x4& hi) {
    f16x2 p0 = __builtin_bit_cast(f16x2, __builtin_amdgcn_cvt_pkrtz(lo[0], lo[1]));
    f16x2 p1 = __builtin_bit_cast(f16x2, __builtin_amdgcn_cvt_pkrtz(lo[2], lo[3]));
    f16x2 p2 = __builtin_bit_cast(f16x2, __builtin_amdgcn_cvt_pkrtz(hi[0], hi[1]));
    f16x2 p3 = __builtin_bit_cast(f16x2, __builtin_amdgcn_cvt_pkrtz(hi[2], hi[3]));
    return (f16x8){p0[0], p0[1], p1[0], p1[1], p2[0], p2[1], p3[0], p3[1]};
}

// X: f32 -> f16 PRE-SWIZZLED dst[m][(k8 ^ (m&7))*8] (R9-verified, for A path)
__global__ __launch_bounds__(256)
void convert_swz_kernel(const float* __restrict__ src, f16* __restrict__ dst) {
    const int idx = blockIdx.x * 256 + threadIdx.x;
    const int m   = idx >> 8;
    const int k8  = idx & 255;
    const int k8s = k8 ^ (m & 7);
    const float* p = src + (size_t)m * Kdim + k8 * 8;
    f32x4 lo = *(const f32x4*)p;
    f32x4 hi = *(const f32x4*)(p + 4);
    *(f16x8*)(dst + (size_t)m * Kdim + k8s * 8) = pack8(lo, hi);
}

// W: f32 -> f16 LINEAR (for direct register loads)
__global__ __launch_bounds__(256)
void convert_lin_kernel(const float* __restrict__ src, f16* __restrict__ dst) {
    const size_t idx = ((size_t)blockIdx.x * 256 + threadIdx.x) * 8;
    f32x4 lo = *(const f32x4*)(src + idx);
    f32x4 hi = *(const f32x4*)(src + idx + 4);
    *(f16x8*)(dst + idx) = pack8(lo, hi);
}

// swizzled LDS read: row stride 128B, byte ^= (row&7)<<4 (0 conflicts)
__device__ __forceinline__ f16x8 lds_frag(const f16* base, int r, int kc) {
    const int b = ((r * BK + kc) * 2) ^ ((r & 7) << 4);
    return *(const f16x8*)((const char*)base + b);
}

__global__ __launch_bounds__(256, 2)
void gemm_a2a_kernel(const f16* __restrict__ Xs, const f16* __restrict__ Wl,
                     float* __restrict__ out) {
    __shared__ f16 sA[BM * BK];   // 16 KiB — A only; B lives in registers

    const int tid  = threadIdx.x;
    const int lane = tid & 63;
    const int wid  = tid >> 6;
    const int wr   = wid >> 1;          // 0..1 -> 64 M-rows
    const int wc   = wid & 1;           // 0..1 -> 64 N-cols

    const int cpx  = NWG >> 3;                       // XCD-bijective swizzle
    const int tile = (blockIdx.x & 7) * cpx + (blockIdx.x >> 3);
    const int bn   = tile & 15;
    const int bm   = tile >> 4;
    const int row0 = bm * BM;
    const int col0 = bn * BN;

    const int lr = lane & 15;
    const int kq = (lane >> 4) * 8;

    f32x4 acc[4][4] = {};

    // A staging (R9-verified): chunk c8 = i*256+tid, linear LDS dest; source
    // pre-swizzled so the LDS image is the XOR-swizzled layout.
    const int c8r[1] = {0};  (void)c8r;
    // B direct: per-frag base pointers (row = col0 + wc*64 + g*16 + lr)
    const f16* pB[4][2];
#pragma unroll
    for (int g = 0; g < 4; ++g)
#pragma unroll
        for (int kk = 0; kk < 2; ++kk)
            pB[g][kk] = Wl + (size_t)(col0 + wc * 64 + g * 16 + lr) * Kdim
                           + kk * 32 + kq;

    for (int t = 0; t < NT; ++t) {
        __syncthreads();   // all waves done computing previous tile (WAR)
        // B(t): 8 x 16B register loads from L2-resident W (issue first)
        f16x8 Bf[4][2];
#pragma unroll
        for (int g = 0; g < 4; ++g)
#pragma unroll
            for (int kk = 0; kk < 2; ++kk)
                Bf[g][kk] = *(const f16x8*)(pB[g][kk] + t * BK);
        // A(t): 4 x global_load_lds dwordx4
#pragma unroll
        for (int i = 0; i < 4; ++i) {
            const int c8 = i * 256 + tid;
            const int r  = c8 >> 3;
            const int cc = (c8 & 7) * 8;
            __builtin_amdgcn_global_load_lds(
                GPTR(Xs + (size_t)(row0 + r) * Kdim + t * BK + cc),
                LPTR(&sA[c8 * 8]), 16, 0, 0);
        }
        __syncthreads();   // drains vmcnt: A in LDS, B in regs

        f16x8 Af[4][2];
#pragma unroll
        for (int f = 0; f < 4; ++f)
#pragma unroll
            for (int kk = 0; kk < 2; ++kk)
                Af[f][kk] = lds_frag(sA, wr * 64 + f * 16 + lr, kk * 32 + kq);

        __builtin_amdgcn_s_setprio(1);
#pragma unroll
        for (int kk = 0; kk < 2; ++kk)
#pragma unroll
            for (int f = 0; f < 4; ++f)
#pragma unroll
                for (int g = 0; g < 4; ++g)
                    acc[f][g] = __builtin_amdgcn_mfma_f32_16x16x32_f16(
                        Af[f][kk], Bf[g][kk], acc[f][g], 0, 0, 0);
        __builtin_amdgcn_s_setprio(0);
    }

    // Epilogue: C/D col=lane&15 (n), row=(lane>>4)*4+j (m); fused all2all:
    // out[(n>>8)*M*256 + m*256 + (n&255)], f32 stores.
#pragma unroll
    for (int mi = 0; mi < 4; ++mi)
#pragma unroll
        for (int ni = 0; ni < 4; ++ni) {
            const int n     = col0 + wc * 64 + ni * 16 + lr;
            const int rbase = row0 + wr * 64 + mi * 16 + (lane >> 4) * 4;
            const size_t obase = (size_t)(n >> 8) * ((size_t)Mdim * 256) + (n & 255);
#pragma unroll
            for (int j = 0; j < 4; ++j)
                out[obase + (size_t)(rbase + j) * 256] = acc[mi][ni][j];
        }
}

// ---- Fallback (R7-verified): direct-f32 reg-staged dbuf 128^2 kernel ----
constexpr int FBM = 128, FBK = 64;
constexpr int FNWG = (Mdim / FBM) * (Ndim / FBM);
__global__ __launch_bounds__(256)
void gemm_a2a_f32_kernel(const float* __restrict__ X, const float* __restrict__ W,
                         float* __restrict__ out) {
    __shared__ f16 sA[2][FBM * FBK];
    __shared__ f16 sB[2][FBM * FBK];
    const int tid  = threadIdx.x;
    const int lane = tid & 63;
    const int wid  = tid >> 6;
    const int wr   = wid >> 1;
    const int wc   = wid & 1;
    const int cpx  = FNWG >> 3;
    const int tile = (blockIdx.x & 7) * cpx + (blockIdx.x >> 3);
    const int bn   = tile & 15;
    const int bm   = tile >> 4;
    const int row0 = bm * FBM;
    const int col0 = bn * FBM;
    f32x4 acc[4][4] = {};
    f32x4 ra[8], rb[8];
    auto load_tile = [&](int t) {
#pragma unroll
        for (int i = 0; i < 4; ++i) {
            const int c8 = i * 256 + tid;
            const int r  = c8 >> 3;
            const int cc = (c8 & 7) * 8;
            const float* pa = X + (size_t)(row0 + r) * Kdim + t * FBK + cc;
            const float* pb = W + (size_t)(col0 + r) * Kdim + t * FBK + cc;
            ra[2*i] = *(const f32x4*)pa; ra[2*i+1] = *(const f32x4*)(pa + 4);
            rb[2*i] = *(const f32x4*)pb; rb[2*i+1] = *(const f32x4*)(pb + 4);
        }
    };
    int cur = 0;
    load_tile(0);
    for (int t = 0; t < Kdim / FBK; ++t) {
#pragma unroll
        for (int i = 0; i < 4; ++i) {
            const int c8 = i * 256 + tid;
            const int sb = (c8 * 16) ^ (((c8 >> 3) & 7) << 4);
            *(f16x8*)((char*)sA[cur] + sb) = pack8(ra[2*i], ra[2*i+1]);
            *(f16x8*)((char*)sB[cur] + sb) = pack8(rb[2*i], rb[2*i+1]);
        }
        if (t + 1 < Kdim / FBK) load_tile(t + 1);
        __syncthreads();
        const f16* Ab = sA[cur];
        const f16* Bb = sB[cur];
#pragma unroll
        for (int kk = 0; kk < FBK; kk += 32) {
            const int kc = kk + (lane >> 4) * 8;
            f16x8 af[4], bfr[4];
#pragma unroll
            for (int f = 0; f < 4; ++f) {
                const int rowA = wr * 64 + f * 16 + (lane & 15);
                af[f] = *(const f16x8*)((const char*)Ab + (((rowA * FBK + kc) * 2) ^ ((rowA & 7) << 4)));
                const int rowB = wc * 64 + f * 16 + (lane & 15);
                bfr[f] = *(const f16x8*)((const char*)Bb + (((rowB * FBK + kc) * 2) ^ ((rowB & 7) << 4)));
            }
#pragma unroll
            for (int mi = 0; mi < 4; ++mi)
#pragma unroll
                for (int ni = 0; ni < 4; ++ni)
                    acc[mi][ni] = __builtin_amdgcn_mfma_f32_16x16x32_f16(
                        af[mi], bfr[ni], acc[mi][ni], 0, 0, 0);
        }
        cur ^= 1;
    }
#pragma unroll
    for (int mi = 0; mi < 4; ++mi)
#pragma unroll
        for (int ni = 0; ni < 4; ++ni) {
            const int n     = col0 + wc * 64 + ni * 16 + (lane & 15);
            const int rbase = row0 + wr * 64 + mi * 16 + (lane >> 4) * 4;
            const size_t obase = (size_t)(n >> 8) * ((size_t)Mdim * 256) + (n & 255);
#pragma unroll
            for (int j = 0; j < 4; ++j)
                out[obase + (size_t)(rbase + j) * 256] = acc[mi][ni][j];
        }
}

extern "C" void kernel_launch(void* const* d_in, const int* in_sizes, int n_in,
                              void* d_out, int out_size, void* d_ws, size_t ws_size,
                              hipStream_t stream) {
    const float* X = (const float*)d_in[0];
    const float* W = (const float*)d_in[1];
    float* out     = (float*)d_out;
    if (ws_size >= WS_NEED) {
        f16* Xs = (f16*)d_ws;
        f16* Wl = Xs + XS_ELEMS;
        hipLaunchKernelGGL(convert_swz_kernel, dim3((int)(XS_ELEMS / 8 / 256)),
                           dim3(256), 0, stream, X, Xs);
        hipLaunchKernelGGL(convert_lin_kernel, dim3((int)(WS_ELEMS / 8 / 256)),
                           dim3(256), 0, stream, W, Wl);
        hipLaunchKernelGGL(gemm_a2a_kernel, dim3(NWG), dim3(256), 0, stream, Xs, Wl, out);
    } else {
        hipLaunchKernelGGL(gemm_a2a_f32_kernel, dim3(FNWG), dim3(256), 0, stream, X, W, out);
    }
}

// Round 19
// 432.144 us; speedup vs baseline: 1.2627x; 1.2627x over previous
//
#include <hip/hip_runtime.h>

// SPModel_6846177870356: y = x@W^T + all2all permute. M=28160, N=K=2048.
// Inputs FP32 (harness-upcast fp16), output FP32.
// Round 19 = R15 (best, 332us GEMM) with the m201 gate discipline:
//  - stage ALL 4 units of tile t+1 at p0 (8 gload_lds issues, WAR-safe:
//    buf dn's readers finished at p3(t-1)'s end barrier)
//  - ONE vmcnt(0) gate per tile at p3 — every load ~3 phases (~1800cyc) old
//    by then, so the drain is ~free; p0/p1 gates removed (R15 had 3 stalls)
//  - everything else identical to R15: 256x256 BK=64 dbuf, 8 waves (2Mx4N),
//    4 quadrant phases, reads pre-barrier, 2 barriers/phase, lgkmcnt(0)+
//    sched_barrier (rule #18), setprio (T5), pre-swizzled f16 globals (R9),
//    XOR ds_read (T2, 0 conflicts), XCD swizzle (T1), fused a2a epilogue.

typedef _Float16 f16;
typedef _Float16 f16x2 __attribute__((ext_vector_type(2)));
typedef _Float16 f16x8 __attribute__((ext_vector_type(8)));
typedef float    f32x4 __attribute__((ext_vector_type(4)));

#define GPTR(p) ((const __attribute__((address_space(1))) void*)(p))
#define LPTR(p) ((__attribute__((address_space(3))) void*)(p))

constexpr int Mdim = 28160;   // 8*44*80
constexpr int Ndim = 2048;
constexpr int Kdim = 2048;
constexpr int BM = 256, BN = 256, BK = 64;
constexpr int NWG = (Mdim / BM) * (Ndim / BN);  // 880 (%8==0)
constexpr int NT  = Kdim / BK;                  // 32
constexpr size_t XS_ELEMS = (size_t)Mdim * Kdim;
constexpr size_t WS_ELEMS = (size_t)Ndim * Kdim;
constexpr size_t WS_NEED  = (XS_ELEMS + WS_ELEMS) * sizeof(f16);

__device__ __forceinline__ f16x8 pack8(const f32x4& lo, const f32x4& hi) {
    f16x2 p0 = __builtin_bit_cast(f16x2, __builtin_amdgcn_cvt_pkrtz(lo[0], lo[1]));
    f16x2 p1 = __builtin_bit_cast(f16x2, __builtin_amdgcn_cvt_pkrtz(lo[2], lo[3]));
    f16x2 p2 = __builtin_bit_cast(f16x2, __builtin_amdgcn_cvt_pkrtz(hi[0], hi[1]));
    f16x2 p3 = __builtin_bit_cast(f16x2, __builtin_amdgcn_cvt_pkrtz(hi[2], hi[3]));
    return (f16x8){p0[0], p0[1], p1[0], p1[1], p2[0], p2[1], p3[0], p3[1]};
}

// f32 [rows x 2048] -> f16 pre-swizzled: dst[m][(k8 ^ (m&7))*8] (R9-verified).
__global__ __launch_bounds__(256)
void convert_kernel(const float* __restrict__ src, f16* __restrict__ dst) {
    const int idx = blockIdx.x * 256 + threadIdx.x;
    const int m   = idx >> 8;
    const int k8  = idx & 255;
    const int k8s = k8 ^ (m & 7);
    const float* p = src + (size_t)m * Kdim + k8 * 8;
    f32x4 lo = *(const f32x4*)p;
    f32x4 hi = *(const f32x4*)(p + 4);
    *(f16x8*)(dst + (size_t)m * Kdim + k8s * 8) = pack8(lo, hi);
}

// swizzled LDS read: row stride 128B, byte ^= (row&7)<<4 (0 conflicts)
__device__ __forceinline__ f16x8 lds_frag(const f16* base, int r, int kc) {
    const int b = ((r * BK + kc) * 2) ^ ((r & 7) << 4);
    return *(const f16x8*)((const char*)base + b);
}

__global__ __launch_bounds__(512, 2)
void gemm_a2a_kernel(const f16* __restrict__ Xs, const f16* __restrict__ Ws,
                     float* __restrict__ out) {
    __shared__ f16 sA[2][BM * BK];   // 32 KiB each, swizzled image
    __shared__ f16 sB[2][BN * BK];   // total 128 KiB

    const int tid  = threadIdx.x;
    const int lane = tid & 63;
    const int wid  = tid >> 6;
    const int wm   = wid >> 2;          // 0..1 -> 128 M-rows
    const int wn   = wid & 3;           // 0..3 -> 64 N-cols

    const int cpx  = NWG >> 3;                       // XCD-bijective swizzle
    const int tile = (blockIdx.x & 7) * cpx + (blockIdx.x >> 3);
    const int bn   = tile & 7;
    const int bm   = tile >> 3;
    const int row0 = bm * BM;
    const int col0 = bn * BN;

    const int lr = lane & 15;
    const int kq = (lane >> 4) * 8;

    f32x4 acc[8][4] = {};

    // staging units (R15-verified): A_u by qm-halves, B_u by qn-halves
    const f16* srcA[2][2]; const f16* srcB[2][2];
    int dstA[2][2], dstB[2][2];
#pragma unroll
    for (int u = 0; u < 2; ++u)
#pragma unroll
        for (int g = 0; g < 2; ++g) {
            const int L  = g * 512 + tid;
            const int rl = L >> 3;
            const int ka = (L & 7) * 8;
            const int ra = (rl & 63) + u * 64 + ((rl & 64) << 1);
            const int rb = (rl & 31) + u * 32 + ((rl >> 5) << 6);
            srcA[u][g] = Xs + (size_t)(row0 + ra) * Kdim + ka;
            srcB[u][g] = Ws + (size_t)(col0 + rb) * Kdim + ka;
            dstA[u][g] = (ra * 8 + (L & 7)) * 8;
            dstB[u][g] = (rb * 8 + (L & 7)) * 8;
        }

#define STAGE_A(T, D, U)                                                     \
    do {                                                                     \
        __builtin_amdgcn_global_load_lds(GPTR(srcA[U][0] + (T) * BK),        \
            LPTR(&sA[D][dstA[U][0]]), 16, 0, 0);                             \
        __builtin_amdgcn_global_load_lds(GPTR(srcA[U][1] + (T) * BK),        \
            LPTR(&sA[D][dstA[U][1]]), 16, 0, 0);                             \
    } while (0)
#define STAGE_B(T, D, U)                                                     \
    do {                                                                     \
        __builtin_amdgcn_global_load_lds(GPTR(srcB[U][0] + (T) * BK),        \
            LPTR(&sB[D][dstB[U][0]]), 16, 0, 0);                             \
        __builtin_amdgcn_global_load_lds(GPTR(srcB[U][1] + (T) * BK),        \
            LPTR(&sB[D][dstB[U][1]]), 16, 0, 0);                             \
    } while (0)

    f16x8 Af[4][2], Bf0[2][2], Bf1[2][2];
    auto readA = [&](const f16* base, int qm) {
#pragma unroll
        for (int f = 0; f < 4; ++f)
#pragma unroll
            for (int kk = 0; kk < 2; ++kk)
                Af[f][kk] = lds_frag(base, wm * 128 + qm * 64 + f * 16 + lr,
                                     kk * 32 + kq);
    };
    auto readB = [&](const f16* base, int qn, f16x8 (&dst)[2][2]) {
#pragma unroll
        for (int g = 0; g < 2; ++g)
#pragma unroll
            for (int kk = 0; kk < 2; ++kk)
                dst[g][kk] = lds_frag(base, wn * 64 + qn * 32 + g * 16 + lr,
                                      kk * 32 + kq);
    };

#define MFMA16(BARR, QM, QN)                                                 \
    do {                                                                     \
        __builtin_amdgcn_s_setprio(1);                                       \
        _Pragma("unroll")                                                    \
        for (int kk = 0; kk < 2; ++kk)                                       \
            _Pragma("unroll")                                                \
            for (int f = 0; f < 4; ++f)                                      \
                _Pragma("unroll")                                            \
                for (int g = 0; g < 2; ++g)                                  \
                    acc[(QM)*4 + f][(QN)*2 + g] =                            \
                        __builtin_amdgcn_mfma_f32_16x16x32_f16(              \
                            Af[f][kk], BARR[g][kk],                          \
                            acc[(QM)*4 + f][(QN)*2 + g], 0, 0, 0);           \
        __builtin_amdgcn_s_setprio(0);                                       \
    } while (0)

#define VM0()   asm volatile("s_waitcnt vmcnt(0)" ::: "memory")
#define BAR()   __builtin_amdgcn_s_barrier()
#define LGKM0() do { asm volatile("s_waitcnt lgkmcnt(0)" ::: "memory");      \
                     __builtin_amdgcn_sched_barrier(0); } while (0)

    // Prologue: stage tile 0 fully; certify.
    STAGE_A(0, 0, 0); STAGE_B(0, 0, 0); STAGE_A(0, 0, 1); STAGE_B(0, 0, 1);
    VM0(); BAR();

    for (int t = 0; t < NT - 1; ++t) {
        const int d  = t & 1;
        const int dn = d ^ 1;
        const int tn = t + 1;
        // p0: q(0,0) — stage ALL of tile t+1 (8 issues); no gate.
        readA(sA[d], 0); readB(sB[d], 0, Bf0);
        STAGE_A(tn, dn, 0); STAGE_B(tn, dn, 0);
        STAGE_A(tn, dn, 1); STAGE_B(tn, dn, 1);
        BAR(); LGKM0();
        MFMA16(Bf0, 0, 0);
        BAR();
        // p1: q(1,0)
        readA(sA[d], 1);
        BAR(); LGKM0();
        MFMA16(Bf0, 1, 0);
        BAR();
        // p2: q(1,1)
        readB(sB[d], 1, Bf1);
        BAR(); LGKM0();
        MFMA16(Bf1, 1, 1);
        BAR();
        // p3: q(0,1) — single gate: tile t+1's loads are ~3 phases old.
        readA(sA[d], 0);
        VM0(); BAR(); LGKM0();
        MFMA16(Bf1, 0, 1);
        BAR();
    }

    // Peeled last tile: no staging, no gate (certified by p3 of NT-2).
    {
        const f16* Ab = sA[(NT - 1) & 1];
        const f16* Bb = sB[(NT - 1) & 1];
        readA(Ab, 0); readB(Bb, 0, Bf0);
        BAR(); LGKM0();
        MFMA16(Bf0, 0, 0);
        BAR();
        readA(Ab, 1);
        BAR(); LGKM0();
        MFMA16(Bf0, 1, 0);
        BAR();
        readB(Bb, 1, Bf1);
        BAR(); LGKM0();
        MFMA16(Bf1, 1, 1);
        BAR();
        readA(Ab, 0);
        LGKM0();
        MFMA16(Bf1, 0, 1);
    }

    // Epilogue: C/D col=lane&15 (n), row=(lane>>4)*4+j (m); fused all2all:
    // out[(n>>8)*M*256 + m*256 + (n&255)], f32 stores.
    const int R0 = row0 + wm * 128;
    const int C0 = col0 + wn * 64;
#pragma unroll
    for (int mi = 0; mi < 8; ++mi)
#pragma unroll
        for (int ni = 0; ni < 4; ++ni) {
            const int n     = C0 + ni * 16 + (lane & 15);
            const int rbase = R0 + mi * 16 + (lane >> 4) * 4;
            const size_t obase = (size_t)(n >> 8) * ((size_t)Mdim * 256) + (n & 255);
#pragma unroll
            for (int j = 0; j < 4; ++j)
                out[obase + (size_t)(rbase + j) * 256] = acc[mi][ni][j];
        }
}

// ---- Fallback (R7-verified): direct-f32 reg-staged dbuf 128^2 kernel ----
constexpr int FBM = 128, FBK = 64;
constexpr int FNWG = (Mdim / FBM) * (Ndim / FBM);
__global__ __launch_bounds__(256)
void gemm_a2a_f32_kernel(const float* __restrict__ X, const float* __restrict__ W,
                         float* __restrict__ out) {
    __shared__ f16 sA[2][FBM * FBK];
    __shared__ f16 sB[2][FBM * FBK];
    const int tid  = threadIdx.x;
    const int lane = tid & 63;
    const int wid  = tid >> 6;
    const int wr   = wid >> 1;
    const int wc   = wid & 1;
    const int cpx  = FNWG >> 3;
    const int tile = (blockIdx.x & 7) * cpx + (blockIdx.x >> 3);
    const int bn   = tile & 15;
    const int bm   = tile >> 4;
    const int row0 = bm * FBM;
    const int col0 = bn * FBM;
    f32x4 acc[4][4] = {};
    f32x4 ra[8], rb[8];
    auto load_tile = [&](int t) {
#pragma unroll
        for (int i = 0; i < 4; ++i) {
            const int c8 = i * 256 + tid;
            const int r  = c8 >> 3;
            const int cc = (c8 & 7) * 8;
            const float* pa = X + (size_t)(row0 + r) * Kdim + t * FBK + cc;
            const float* pb = W + (size_t)(col0 + r) * Kdim + t * FBK + cc;
            ra[2*i] = *(const f32x4*)pa; ra[2*i+1] = *(const f32x4*)(pa + 4);
            rb[2*i] = *(const f32x4*)pb; rb[2*i+1] = *(const f32x4*)(pb + 4);
        }
    };
    int cur = 0;
    load_tile(0);
    for (int t = 0; t < Kdim / FBK; ++t) {
#pragma unroll
        for (int i = 0; i < 4; ++i) {
            const int c8 = i * 256 + tid;
            const int sb = (c8 * 16) ^ (((c8 >> 3) & 7) << 4);
            *(f16x8*)((char*)sA[cur] + sb) = pack8(ra[2*i], ra[2*i+1]);
            *(f16x8*)((char*)sB[cur] + sb) = pack8(rb[2*i], rb[2*i+1]);
        }
        if (t + 1 < Kdim / FBK) load_tile(t + 1);
        __syncthreads();
        const f16* Ab = sA[cur];
        const f16* Bb = sB[cur];
#pragma unroll
        for (int kk = 0; kk < FBK; kk += 32) {
            const int kc = kk + (lane >> 4) * 8;
            f16x8 af[4], bfr[4];
#pragma unroll
            for (int f = 0; f < 4; ++f) {
                const int rowA = wr * 64 + f * 16 + (lane & 15);
                af[f] = *(const f16x8*)((const char*)Ab + (((rowA * FBK + kc) * 2) ^ ((rowA & 7) << 4)));
                const int rowB = wc * 64 + f * 16 + (lane & 15);
                bfr[f] = *(const f16x8*)((const char*)Bb + (((rowB * FBK + kc) * 2) ^ ((rowB & 7) << 4)));
            }
#pragma unroll
            for (int mi = 0; mi < 4; ++mi)
#pragma unroll
                for (int ni = 0; ni < 4; ++ni)
                    acc[mi][ni] = __builtin_amdgcn_mfma_f32_16x16x32_f16(
                        af[mi], bfr[ni], acc[mi][ni], 0, 0, 0);
        }
        cur ^= 1;
    }
#pragma unroll
    for (int mi = 0; mi < 4; ++mi)
#pragma unroll
        for (int ni = 0; ni < 4; ++ni) {
            const int n     = col0 + wc * 64 + ni * 16 + (lane & 15);
            const int rbase = row0 + wr * 64 + mi * 16 + (lane >> 4) * 4;
            const size_t obase = (size_t)(n >> 8) * ((size_t)Mdim * 256) + (n & 255);
#pragma unroll
            for (int j = 0; j < 4; ++j)
                out[obase + (size_t)(rbase + j) * 256] = acc[mi][ni][j];
        }
}

extern "C" void kernel_launch(void* const* d_in, const int* in_sizes, int n_in,
                              void* d_out, int out_size, void* d_ws, size_t ws_size,
                              hipStream_t stream) {
    const float* X = (const float*)d_in[0];
    const float* W = (const float*)d_in[1];
    float* out     = (float*)d_out;
    if (ws_size >= WS_NEED) {
        f16* Xs = (f16*)d_ws;
        f16* Ws = Xs + XS_ELEMS;
        hipLaunchKernelGGL(convert_kernel, dim3((int)(XS_ELEMS / 8 / 256)), dim3(256),
                           0, stream, X, Xs);
        hipLaunchKernelGGL(convert_kernel, dim3((int)(WS_ELEMS / 8 / 256)), dim3(256),
                           0, stream, W, Ws);
        hipLaunchKernelGGL(gemm_a2a_kernel, dim3(NWG), dim3(512), 0, stream, Xs, Ws, out);
    } else {
        hipLaunchKernelGGL(gemm_a2a_f32_kernel, dim3(FNWG), dim3(256), 0, stream, X, W, out);
    }
}

// Round 20
// 431.892 us; speedup vs baseline: 1.2635x; 1.0006x over previous
//
#include <hip/hip_runtime.h>

// SPModel_6846177870356: y = x@W^T + all2all permute. M=28160, N=K=2048.
// Inputs FP32 (harness-upcast fp16), output FP32.
// Round 19 = R15 (best, 332us GEMM) with the m201 gate discipline:
//  - stage ALL 4 units of tile t+1 at p0 (8 gload_lds issues, WAR-safe:
//    buf dn's readers finished at p3(t-1)'s end barrier)
//  - ONE vmcnt(0) gate per tile at p3 — every load ~3 phases (~1800cyc) old
//    by then, so the drain is ~free; p0/p1 gates removed (R15 had 3 stalls)
//  - everything else identical to R15: 256x256 BK=64 dbuf, 8 waves (2Mx4N),
//    4 quadrant phases, reads pre-barrier, 2 barriers/phase, lgkmcnt(0)+
//    sched_barrier (rule #18), setprio (T5), pre-swizzled f16 globals (R9),
//    XOR ds_read (T2, 0 conflicts), XCD swizzle (T1), fused a2a epilogue.

typedef _Float16 f16;
typedef _Float16 f16x2 __attribute__((ext_vector_type(2)));
typedef _Float16 f16x8 __attribute__((ext_vector_type(8)));
typedef float    f32x4 __attribute__((ext_vector_type(4)));

#define GPTR(p) ((const __attribute__((address_space(1))) void*)(p))
#define LPTR(p) ((__attribute__((address_space(3))) void*)(p))

constexpr int Mdim = 28160;   // 8*44*80
constexpr int Ndim = 2048;
constexpr int Kdim = 2048;
constexpr int BM = 256, BN = 256, BK = 64;
constexpr int NWG = (Mdim / BM) * (Ndim / BN);  // 880 (%8==0)
constexpr int NT  = Kdim / BK;                  // 32
constexpr size_t XS_ELEMS = (size_t)Mdim * Kdim;
constexpr size_t WS_ELEMS = (size_t)Ndim * Kdim;
constexpr size_t WS_NEED  = (XS_ELEMS + WS_ELEMS) * sizeof(f16);

__device__ __forceinline__ f16x8 pack8(const f32x4& lo, const f32x4& hi) {
    f16x2 p0 = __builtin_bit_cast(f16x2, __builtin_amdgcn_cvt_pkrtz(lo[0], lo[1]));
    f16x2 p1 = __builtin_bit_cast(f16x2, __builtin_amdgcn_cvt_pkrtz(lo[2], lo[3]));
    f16x2 p2 = __builtin_bit_cast(f16x2, __builtin_amdgcn_cvt_pkrtz(hi[0], hi[1]));
    f16x2 p3 = __builtin_bit_cast(f16x2, __builtin_amdgcn_cvt_pkrtz(hi[2], hi[3]));
    return (f16x8){p0[0], p0[1], p1[0], p1[1], p2[0], p2[1], p3[0], p3[1]};
}

// f32 [rows x 2048] -> f16 pre-swizzled: dst[m][(k8 ^ (m&7))*8] (R9-verified).
__global__ __launch_bounds__(256)
void convert_kernel(const float* __restrict__ src, f16* __restrict__ dst) {
    const int idx = blockIdx.x * 256 + threadIdx.x;
    const int m   = idx >> 8;
    const int k8  = idx & 255;
    const int k8s = k8 ^ (m & 7);
    const float* p = src + (size_t)m * Kdim + k8 * 8;
    f32x4 lo = *(const f32x4*)p;
    f32x4 hi = *(const f32x4*)(p + 4);
    *(f16x8*)(dst + (size_t)m * Kdim + k8s * 8) = pack8(lo, hi);
}

// swizzled LDS read: row stride 128B, byte ^= (row&7)<<4 (0 conflicts)
__device__ __forceinline__ f16x8 lds_frag(const f16* base, int r, int kc) {
    const int b = ((r * BK + kc) * 2) ^ ((r & 7) << 4);
    return *(const f16x8*)((const char*)base + b);
}

__global__ __launch_bounds__(512, 2)
void gemm_a2a_kernel(const f16* __restrict__ Xs, const f16* __restrict__ Ws,
                     float* __restrict__ out) {
    __shared__ f16 sA[2][BM * BK];   // 32 KiB each, swizzled image
    __shared__ f16 sB[2][BN * BK];   // total 128 KiB

    const int tid  = threadIdx.x;
    const int lane = tid & 63;
    const int wid  = tid >> 6;
    const int wm   = wid >> 2;          // 0..1 -> 128 M-rows
    const int wn   = wid & 3;           // 0..3 -> 64 N-cols

    const int cpx  = NWG >> 3;                       // XCD-bijective swizzle
    const int tile = (blockIdx.x & 7) * cpx + (blockIdx.x >> 3);
    const int bn   = tile & 7;
    const int bm   = tile >> 3;
    const int row0 = bm * BM;
    const int col0 = bn * BN;

    const int lr = lane & 15;
    const int kq = (lane >> 4) * 8;

    f32x4 acc[8][4] = {};

    // staging units (R15-verified): A_u by qm-halves, B_u by qn-halves
    const f16* srcA[2][2]; const f16* srcB[2][2];
    int dstA[2][2], dstB[2][2];
#pragma unroll
    for (int u = 0; u < 2; ++u)
#pragma unroll
        for (int g = 0; g < 2; ++g) {
            const int L  = g * 512 + tid;
            const int rl = L >> 3;
            const int ka = (L & 7) * 8;
            const int ra = (rl & 63) + u * 64 + ((rl & 64) << 1);
            const int rb = (rl & 31) + u * 32 + ((rl >> 5) << 6);
            srcA[u][g] = Xs + (size_t)(row0 + ra) * Kdim + ka;
            srcB[u][g] = Ws + (size_t)(col0 + rb) * Kdim + ka;
            dstA[u][g] = (ra * 8 + (L & 7)) * 8;
            dstB[u][g] = (rb * 8 + (L & 7)) * 8;
        }

#define STAGE_A(T, D, U)                                                     \
    do {                                                                     \
        __builtin_amdgcn_global_load_lds(GPTR(srcA[U][0] + (T) * BK),        \
            LPTR(&sA[D][dstA[U][0]]), 16, 0, 0);                             \
        __builtin_amdgcn_global_load_lds(GPTR(srcA[U][1] + (T) * BK),        \
            LPTR(&sA[D][dstA[U][1]]), 16, 0, 0);                             \
    } while (0)
#define STAGE_B(T, D, U)                                                     \
    do {                                                                     \
        __builtin_amdgcn_global_load_lds(GPTR(srcB[U][0] + (T) * BK),        \
            LPTR(&sB[D][dstB[U][0]]), 16, 0, 0);                             \
        __builtin_amdgcn_global_load_lds(GPTR(srcB[U][1] + (T) * BK),        \
            LPTR(&sB[D][dstB[U][1]]), 16, 0, 0);                             \
    } while (0)

    f16x8 Af[4][2], Bf0[2][2], Bf1[2][2];
    auto readA = [&](const f16* base, int qm) {
#pragma unroll
        for (int f = 0; f < 4; ++f)
#pragma unroll
            for (int kk = 0; kk < 2; ++kk)
                Af[f][kk] = lds_frag(base, wm * 128 + qm * 64 + f * 16 + lr,
                                     kk * 32 + kq);
    };
    auto readB = [&](const f16* base, int qn, f16x8 (&dst)[2][2]) {
#pragma unroll
        for (int g = 0; g < 2; ++g)
#pragma unroll
            for (int kk = 0; kk < 2; ++kk)
                dst[g][kk] = lds_frag(base, wn * 64 + qn * 32 + g * 16 + lr,
                                      kk * 32 + kq);
    };

#define MFMA16(BARR, QM, QN)                                                 \
    do {                                                                     \
        __builtin_amdgcn_s_setprio(1);                                       \
        _Pragma("unroll")                                                    \
        for (int kk = 0; kk < 2; ++kk)                                       \
            _Pragma("unroll")                                                \
            for (int f = 0; f < 4; ++f)                                      \
                _Pragma("unroll")                                            \
                for (int g = 0; g < 2; ++g)                                  \
                    acc[(QM)*4 + f][(QN)*2 + g] =                            \
                        __builtin_amdgcn_mfma_f32_16x16x32_f16(              \
                            Af[f][kk], BARR[g][kk],                          \
                            acc[(QM)*4 + f][(QN)*2 + g], 0, 0, 0);           \
        __builtin_amdgcn_s_setprio(0);                                       \
    } while (0)

#define VM0()   asm volatile("s_waitcnt vmcnt(0)" ::: "memory")
#define BAR()   __builtin_amdgcn_s_barrier()
#define LGKM0() do { asm volatile("s_waitcnt lgkmcnt(0)" ::: "memory");      \
                     __builtin_amdgcn_sched_barrier(0); } while (0)

    // Prologue: stage tile 0 fully; certify.
    STAGE_A(0, 0, 0); STAGE_B(0, 0, 0); STAGE_A(0, 0, 1); STAGE_B(0, 0, 1);
    VM0(); BAR();

    for (int t = 0; t < NT - 1; ++t) {
        const int d  = t & 1;
        const int dn = d ^ 1;
        const int tn = t + 1;
        // p0: q(0,0) — stage ALL of tile t+1 (8 issues); no gate.
        readA(sA[d], 0); readB(sB[d], 0, Bf0);
        STAGE_A(tn, dn, 0); STAGE_B(tn, dn, 0);
        STAGE_A(tn, dn, 1); STAGE_B(tn, dn, 1);
        BAR(); LGKM0();
        MFMA16(Bf0, 0, 0);
        BAR();
        // p1: q(1,0)
        readA(sA[d], 1);
        BAR(); LGKM0();
        MFMA16(Bf0, 1, 0);
        BAR();
        // p2: q(1,1)
        readB(sB[d], 1, Bf1);
        BAR(); LGKM0();
        MFMA16(Bf1, 1, 1);
        BAR();
        // p3: q(0,1) — single gate: tile t+1's loads are ~3 phases old.
        readA(sA[d], 0);
        VM0(); BAR(); LGKM0();
        MFMA16(Bf1, 0, 1);
        BAR();
    }

    // Peeled last tile: no staging, no gate (certified by p3 of NT-2).
    {
        const f16* Ab = sA[(NT - 1) & 1];
        const f16* Bb = sB[(NT - 1) & 1];
        readA(Ab, 0); readB(Bb, 0, Bf0);
        BAR(); LGKM0();
        MFMA16(Bf0, 0, 0);
        BAR();
        readA(Ab, 1);
        BAR(); LGKM0();
        MFMA16(Bf0, 1, 0);
        BAR();
        readB(Bb, 1, Bf1);
        BAR(); LGKM0();
        MFMA16(Bf1, 1, 1);
        BAR();
        readA(Ab, 0);
        LGKM0();
        MFMA16(Bf1, 0, 1);
    }

    // Epilogue: C/D col=lane&15 (n), row=(lane>>4)*4+j (m); fused all2all:
    // out[(n>>8)*M*256 + m*256 + (n&255)], f32 stores.
    const int R0 = row0 + wm * 128;
    const int C0 = col0 + wn * 64;
#pragma unroll
    for (int mi = 0; mi < 8; ++mi)
#pragma unroll
        for (int ni = 0; ni < 4; ++ni) {
            const int n     = C0 + ni * 16 + (lane & 15);
            const int rbase = R0 + mi * 16 + (lane >> 4) * 4;
            const size_t obase = (size_t)(n >> 8) * ((size_t)Mdim * 256) + (n & 255);
#pragma unroll
            for (int j = 0; j < 4; ++j)
                out[obase + (size_t)(rbase + j) * 256] = acc[mi][ni][j];
        }
}

// ---- Fallback (R7-verified): direct-f32 reg-staged dbuf 128^2 kernel ----
constexpr int FBM = 128, FBK = 64;
constexpr int FNWG = (Mdim / FBM) * (Ndim / FBM);
__global__ __launch_bounds__(256)
void gemm_a2a_f32_kernel(const float* __restrict__ X, const float* __restrict__ W,
                         float* __restrict__ out) {
    __shared__ f16 sA[2][FBM * FBK];
    __shared__ f16 sB[2][FBM * FBK];
    const int tid  = threadIdx.x;
    const int lane = tid & 63;
    const int wid  = tid >> 6;
    const int wr   = wid >> 1;
    const int wc   = wid & 1;
    const int cpx  = FNWG >> 3;
    const int tile = (blockIdx.x & 7) * cpx + (blockIdx.x >> 3);
    const int bn   = tile & 15;
    const int bm   = tile >> 4;
    const int row0 = bm * FBM;
    const int col0 = bn * FBM;
    f32x4 acc[4][4] = {};
    f32x4 ra[8], rb[8];
    auto load_tile = [&](int t) {
#pragma unroll
        for (int i = 0; i < 4; ++i) {
            const int c8 = i * 256 + tid;
            const int r  = c8 >> 3;
            const int cc = (c8 & 7) * 8;
            const float* pa = X + (size_t)(row0 + r) * Kdim + t * FBK + cc;
            const float* pb = W + (size_t)(col0 + r) * Kdim + t * FBK + cc;
            ra[2*i] = *(const f32x4*)pa; ra[2*i+1] = *(const f32x4*)(pa + 4);
            rb[2*i] = *(const f32x4*)pb; rb[2*i+1] = *(const f32x4*)(pb + 4);
        }
    };
    int cur = 0;
    load_tile(0);
    for (int t = 0; t < Kdim / FBK; ++t) {
#pragma unroll
        for (int i = 0; i < 4; ++i) {
            const int c8 = i * 256 + tid;
            const int sb = (c8 * 16) ^ (((c8 >> 3) & 7) << 4);
            *(f16x8*)((char*)sA[cur] + sb) = pack8(ra[2*i], ra[2*i+1]);
            *(f16x8*)((char*)sB[cur] + sb) = pack8(rb[2*i], rb[2*i+1]);
        }
        if (t + 1 < Kdim / FBK) load_tile(t + 1);
        __syncthreads();
        const f16* Ab = sA[cur];
        const f16* Bb = sB[cur];
#pragma unroll
        for (int kk = 0; kk < FBK; kk += 32) {
            const int kc = kk + (lane >> 4) * 8;
            f16x8 af[4], bfr[4];
#pragma unroll
            for (int f = 0; f < 4; ++f) {
                const int rowA = wr * 64 + f * 16 + (lane & 15);
                af[f] = *(const f16x8*)((const char*)Ab + (((rowA * FBK + kc) * 2) ^ ((rowA & 7) << 4)));
                const int rowB = wc * 64 + f * 16 + (lane & 15);
                bfr[f] = *(const f16x8*)((const char*)Bb + (((rowB * FBK + kc) * 2) ^ ((rowB & 7) << 4)));
            }
#pragma unroll
            for (int mi = 0; mi < 4; ++mi)
#pragma unroll
                for (int ni = 0; ni < 4; ++ni)
                    acc[mi][ni] = __builtin_amdgcn_mfma_f32_16x16x32_f16(
                        af[mi], bfr[ni], acc[mi][ni], 0, 0, 0);
        }
        cur ^= 1;
    }
#pragma unroll
    for (int mi = 0; mi < 4; ++mi)
#pragma unroll
        for (int ni = 0; ni < 4; ++ni) {
            const int n     = col0 + wc * 64 + ni * 16 + (lane & 15);
            const int rbase = row0 + wr * 64 + mi * 16 + (lane >> 4) * 4;
            const size_t obase = (size_t)(n >> 8) * ((size_t)Mdim * 256) + (n & 255);
#pragma unroll
            for (int j = 0; j < 4; ++j)
                out[obase + (size_t)(rbase + j) * 256] = acc[mi][ni][j];
        }
}

extern "C" void kernel_launch(void* const* d_in, const int* in_sizes, int n_in,
                              void* d_out, int out_size, void* d_ws, size_t ws_size,
                              hipStream_t stream) {
    const float* X = (const float*)d_in[0];
    const float* W = (const float*)d_in[1];
    float* out     = (float*)d_out;
    if (ws_size >= WS_NEED) {
        f16* Xs = (f16*)d_ws;
        f16* Ws = Xs + XS_ELEMS;
        hipLaunchKernelGGL(convert_kernel, dim3((int)(XS_ELEMS / 8 / 256)), dim3(256),
                           0, stream, X, Xs);
        hipLaunchKernelGGL(convert_kernel, dim3((int)(WS_ELEMS / 8 / 256)), dim3(256),
                           0, stream, W, Ws);
        hipLaunchKernelGGL(gemm_a2a_kernel, dim3(NWG), dim3(512), 0, stream, Xs, Ws, out);
    } else {
        hipLaunchKernelGGL(gemm_a2a_f32_kernel, dim3(FNWG), dim3(256), 0, stream, X, W, out);
    }
}

// Round 21
// 349.961 us; speedup vs baseline: 1.5593x; 1.2341x over previous
//
#include <hip/hip_runtime.h>

// SPModel_6846177870356: y = x@W^T + all2all permute. M=28160, N=K=2048.
// Inputs FP32 (harness-upcast fp16), output FP32.
// Round 21: R11 buffering (BK=32, TRIPLE buffer, stagger-2) x R15 skeleton
// (reads pre-barrier, 2 barriers/phase, LGKM0+sched_barrier, setprio).
// ONE gate per K-tile: vmcnt(4) at p1 — drains only tile t+1's units
// (staged 4 phases earlier, ~free), leaves t+2's 4 units flying.
// Induction H(t): after gate at p1(t), outstanding = {t+2 units}, all
// tiles <= t+1 certified. Zero frag re-reads. Pre-swizzled f16 globals
// (64B-row bijective XOR image), XCD swizzle, fused all2all f32 epilogue.

typedef _Float16 f16;
typedef _Float16 f16x2 __attribute__((ext_vector_type(2)));
typedef _Float16 f16x8 __attribute__((ext_vector_type(8)));
typedef float    f32x4 __attribute__((ext_vector_type(4)));

#define GPTR(p) ((const __attribute__((address_space(1))) void*)(p))
#define LPTR(p) ((__attribute__((address_space(3))) void*)(p))

constexpr int Mdim = 28160;   // 8*44*80
constexpr int Ndim = 2048;
constexpr int Kdim = 2048;
constexpr int BM = 256, BN = 256, BK = 32;
constexpr int NWG = (Mdim / BM) * (Ndim / BN);  // 880 (%8==0)
constexpr int NT  = Kdim / BK;                  // 64
constexpr size_t XS_ELEMS = (size_t)Mdim * Kdim;
constexpr size_t WS_ELEMS = (size_t)Ndim * Kdim;
constexpr size_t WS_NEED  = (XS_ELEMS + WS_ELEMS) * sizeof(f16);

__device__ __forceinline__ f16x8 pack8(const f32x4& lo, const f32x4& hi) {
    f16x2 p0 = __builtin_bit_cast(f16x2, __builtin_amdgcn_cvt_pkrtz(lo[0], lo[1]));
    f16x2 p1 = __builtin_bit_cast(f16x2, __builtin_amdgcn_cvt_pkrtz(lo[2], lo[3]));
    f16x2 p2 = __builtin_bit_cast(f16x2, __builtin_amdgcn_cvt_pkrtz(hi[0], hi[1]));
    f16x2 p3 = __builtin_bit_cast(f16x2, __builtin_amdgcn_cvt_pkrtz(hi[2], hi[3]));
    return (f16x8){p0[0], p0[1], p1[0], p1[1], p2[0], p2[1], p3[0], p3[1]};
}

// f32 -> f16 with the BK=32 tile swizzle image applied:
// within each (256-row, 32-k) tile, source (r, kt) lands at tile byte
// beta = (r*64 + kt*16) ^ ((r&7)<<4)  [bijective; crosses rows via bit 6].
__global__ __launch_bounds__(256)
void convert_kernel(const float* __restrict__ src, f16* __restrict__ dst) {
    const int idx = blockIdx.x * 256 + threadIdx.x;
    const int m   = idx >> 8;            // source row
    const int k8  = idx & 255;           // source 8-elem chunk in row
    const int t   = k8 >> 2;             // k-tile (32 elems = 4 chunks)
    const int kt  = k8 & 3;
    const int r   = m & 255;             // row within 256-row tile
    int beta = (r << 6) | (kt << 4);
    beta ^= (r & 7) << 4;
    const int rd  = beta >> 6;           // dest row within tile
    const int ktd = (beta >> 4) & 3;     // dest k-chunk
    const float* p = src + (size_t)m * Kdim + k8 * 8;
    f32x4 lo = *(const f32x4*)p;
    f32x4 hi = *(const f32x4*)(p + 4);
    *(f16x8*)(dst + (size_t)((m - r) + rd) * Kdim + t * 32 + ktd * 8) =
        pack8(lo, hi);
}

// swizzled LDS read: row stride 64B (BK=32), byte ^= (row&7)<<4 (2-way max)
__device__ __forceinline__ f16x8 lds_frag(const f16* base, int r, int kc) {
    const int b = ((r * BK + kc) * 2) ^ ((r & 7) << 4);
    return *(const f16x8*)((const char*)base + b);
}

__global__ __launch_bounds__(512, 2)
void gemm_a2a_kernel(const f16* __restrict__ Xs, const f16* __restrict__ Ws,
                     float* __restrict__ out) {
    __shared__ f16 sA[3][BM * BK];   // 16 KiB each (swizzled tile image)
    __shared__ f16 sB[3][BN * BK];   // total 96 KiB

    const int tid  = threadIdx.x;
    const int lane = tid & 63;
    const int wid  = tid >> 6;
    const int wm   = wid >> 2;          // 0..1 -> 128 M-rows
    const int wn   = wid & 3;           // 0..3 -> 64 N-cols

    const int cpx  = NWG >> 3;                       // XCD-bijective swizzle
    const int tile = (blockIdx.x & 7) * cpx + (blockIdx.x >> 3);
    const int bn   = tile & 7;
    const int bm   = tile >> 3;
    const int row0 = bm * BM;
    const int col0 = bn * BN;

    const int lr = lane & 15;
    const int kq = (lane >> 4) * 8;     // k-offset within BK=32

    f32x4 acc[8][4] = {};

    // Unit tile-byte per thread (1 gload_lds per unit; 512 thr x 16B = 8KB):
    // A_u0 = tile rows {0-63}u{128-191} (qm=0), A_u1 = +64; B_u0 = rows
    // 0-127, B_u1 = rows 128-255. Per-wave dst is base + lane*16 (G21 ok).
    const int betaA0 = (tid < 256) ? tid * 16 : 8192 + (tid - 256) * 16;
    const int betaA1 = betaA0 + 4096;
    const int betaB0 = tid * 16;
    const int betaB1 = 8192 + tid * 16;
    // Source element offsets (Xs/Ws hold the swizzled tile image linearly):
    auto srcoff = [&](int beta) {
        return (size_t)(beta >> 6) * Kdim + ((beta >> 4) & 3) * 8;
    };
    const size_t sA0 = srcoff(betaA0), sA1 = srcoff(betaA1);
    const size_t sB0 = srcoff(betaB0), sB1 = srcoff(betaB1);
    const f16* Xb = Xs + (size_t)row0 * Kdim;
    const f16* Wb = Ws + (size_t)col0 * Kdim;

#define STAGE_A2(T, DA)                                                      \
    do {                                                                     \
        __builtin_amdgcn_global_load_lds(GPTR(Xb + sA0 + (T) * BK),          \
            LPTR((char*)(DA) + betaA0), 16, 0, 0);                           \
        __builtin_amdgcn_global_load_lds(GPTR(Xb + sA1 + (T) * BK),          \
            LPTR((char*)(DA) + betaA1), 16, 0, 0);                           \
    } while (0)
#define STAGE_B2(T, DB)                                                      \
    do {                                                                     \
        __builtin_amdgcn_global_load_lds(GPTR(Wb + sB0 + (T) * BK),          \
            LPTR((char*)(DB) + betaB0), 16, 0, 0);                           \
        __builtin_amdgcn_global_load_lds(GPTR(Wb + sB1 + (T) * BK),          \
            LPTR((char*)(DB) + betaB1), 16, 0, 0);                           \
    } while (0)

    f16x8 Af[4], Bf[4];
    auto readA = [&](const f16* base, int qm) {
#pragma unroll
        for (int f = 0; f < 4; ++f)
            Af[f] = lds_frag(base, wm * 128 + qm * 64 + f * 16 + lr, kq);
    };
    auto readB = [&](const f16* base) {
#pragma unroll
        for (int g = 0; g < 4; ++g)
            Bf[g] = lds_frag(base, wn * 64 + g * 16 + lr, kq);
    };

#define MFMA16(QM)                                                          \
    do {                                                                    \
        __builtin_amdgcn_s_setprio(1);                                      \
        _Pragma("unroll")                                                   \
        for (int f = 0; f < 4; ++f)                                         \
            _Pragma("unroll")                                               \
            for (int g = 0; g < 4; ++g)                                     \
                acc[(QM)*4 + f][g] =                                        \
                    __builtin_amdgcn_mfma_f32_16x16x32_f16(                 \
                        Af[f], Bf[g], acc[(QM)*4 + f][g], 0, 0, 0);         \
        __builtin_amdgcn_s_setprio(0);                                      \
    } while (0)

#define VM(N)   asm volatile("s_waitcnt vmcnt(" #N ")" ::: "memory")
#define BAR()   __builtin_amdgcn_s_barrier()
#define LGKM0() do { asm volatile("s_waitcnt lgkmcnt(0)" ::: "memory");     \
                     __builtin_amdgcn_sched_barrier(0); } while (0)

    f16 *cA = sA[0], *nA = sA[1], *gA = sA[2];
    f16 *cB = sB[0], *nB = sB[1], *gB = sB[2];

    // Prologue: stage tile 0 -> buf0, tile 1 -> buf1 (8 loads); certify t0.
    STAGE_A2(0, cA); STAGE_B2(0, cB);
    STAGE_A2(1, nA); STAGE_B2(1, nB);
    VM(4); BAR();                       // t0 certified; t1's 4 in flight

    for (int t = 0; t < NT - 2; ++t) {
        // p0: qm=0 — reads of tile t certified by previous tile's gate
        readA(cA, 0); readB(cB);
        STAGE_A2(t + 2, gA);
        BAR(); LGKM0();
        MFMA16(0);
        BAR();
        // p1: qm=1 (B held in regs)
        readA(cA, 1);
        STAGE_B2(t + 2, gB);
        VM(4); BAR(); LGKM0();          // drains tile t+1's 4 units (old)
        MFMA16(1);
        BAR();
        // rotate: cur <- next <- stage <- cur
        f16* tA = cA; cA = nA; nA = gA; gA = tA;
        f16* tB = cB; cB = nB; nB = gB; gB = tB;
    }
    // Peel t = NT-2: no staging; gate VM(0) certifies tile NT-1 (loads old).
    {
        readA(cA, 0); readB(cB);
        BAR(); LGKM0();
        MFMA16(0);
        BAR();
        readA(cA, 1);
        VM(0); BAR(); LGKM0();
        MFMA16(1);
        BAR();
        f16* tA = cA; cA = nA; nA = gA; gA = tA;
        f16* tB = cB; cB = nB; nB = gB; gB = tB;
    }
    // Peel t = NT-1: everything certified.
    {
        readA(cA, 0); readB(cB);
        BAR(); LGKM0();
        MFMA16(0);
        BAR();
        readA(cA, 1);
        LGKM0();
        MFMA16(1);
    }

    // Epilogue: C/D col=lane&15 (n), row=(lane>>4)*4+j (m); fused all2all:
    // out[(n>>8)*M*256 + m*256 + (n&255)], f32 stores.
    const int R0 = row0 + wm * 128;
    const int C0 = col0 + wn * 64;
#pragma unroll
    for (int mi = 0; mi < 8; ++mi)
#pragma unroll
        for (int ni = 0; ni < 4; ++ni) {
            const int n     = C0 + ni * 16 + lr;
            const int rbase = R0 + mi * 16 + (lane >> 4) * 4;
            const size_t obase = (size_t)(n >> 8) * ((size_t)Mdim * 256) + (n & 255);
#pragma unroll
            for (int j = 0; j < 4; ++j)
                out[obase + (size_t)(rbase + j) * 256] = acc[mi][ni][j];
        }
}

// ---- Fallback (R7-verified): direct-f32 reg-staged dbuf 128^2 kernel ----
constexpr int FBM = 128, FBK = 64;
constexpr int FNWG = (Mdim / FBM) * (Ndim / FBM);
__global__ __launch_bounds__(256)
void gemm_a2a_f32_kernel(const float* __restrict__ X, const float* __restrict__ W,
                         float* __restrict__ out) {
    __shared__ f16 sA[2][FBM * FBK];
    __shared__ f16 sB[2][FBM * FBK];
    const int tid  = threadIdx.x;
    const int lane = tid & 63;
    const int wid  = tid >> 6;
    const int wr   = wid >> 1;
    const int wc   = wid & 1;
    const int cpx  = FNWG >> 3;
    const int tile = (blockIdx.x & 7) * cpx + (blockIdx.x >> 3);
    const int bn   = tile & 15;
    const int bm   = tile >> 4;
    const int row0 = bm * FBM;
    const int col0 = bn * FBM;
    f32x4 acc[4][4] = {};
    f32x4 ra[8], rb[8];
    auto load_tile = [&](int t) {
#pragma unroll
        for (int i = 0; i < 4; ++i) {
            const int c8 = i * 256 + tid;
            const int r  = c8 >> 3;
            const int cc = (c8 & 7) * 8;
            const float* pa = X + (size_t)(row0 + r) * Kdim + t * FBK + cc;
            const float* pb = W + (size_t)(col0 + r) * Kdim + t * FBK + cc;
            ra[2*i] = *(const f32x4*)pa; ra[2*i+1] = *(const f32x4*)(pa + 4);
            rb[2*i] = *(const f32x4*)pb; rb[2*i+1] = *(const f32x4*)(pb + 4);
        }
    };
    int cur = 0;
    load_tile(0);
    for (int t = 0; t < Kdim / FBK; ++t) {
#pragma unroll
        for (int i = 0; i < 4; ++i) {
            const int c8 = i * 256 + tid;
            const int sb = (c8 * 16) ^ (((c8 >> 3) & 7) << 4);
            *(f16x8*)((char*)sA[cur] + sb) = pack8(ra[2*i], ra[2*i+1]);
            *(f16x8*)((char*)sB[cur] + sb) = pack8(rb[2*i], rb[2*i+1]);
        }
        if (t + 1 < Kdim / FBK) load_tile(t + 1);
        __syncthreads();
        const f16* Ab = sA[cur];
        const f16* Bb = sB[cur];
#pragma unroll
        for (int kk = 0; kk < FBK; kk += 32) {
            const int kc = kk + (lane >> 4) * 8;
            f16x8 af[4], bfr[4];
#pragma unroll
            for (int f = 0; f < 4; ++f) {
                const int rowA = wr * 64 + f * 16 + (lane & 15);
                af[f] = *(const f16x8*)((const char*)Ab + (((rowA * FBK + kc) * 2) ^ ((rowA & 7) << 4)));
                const int rowB = wc * 64 + f * 16 + (lane & 15);
                bfr[f] = *(const f16x8*)((const char*)Bb + (((rowB * FBK + kc) * 2) ^ ((rowB & 7) << 4)));
            }
#pragma unroll
            for (int mi = 0; mi < 4; ++mi)
#pragma unroll
                for (int ni = 0; ni < 4; ++ni)
                    acc[mi][ni] = __builtin_amdgcn_mfma_f32_16x16x32_f16(
                        af[mi], bfr[ni], acc[mi][ni], 0, 0, 0);
        }
        cur ^= 1;
    }
#pragma unroll
    for (int mi = 0; mi < 4; ++mi)
#pragma unroll
        for (int ni = 0; ni < 4; ++ni) {
            const int n     = col0 + wc * 64 + ni * 16 + (lane & 15);
            const int rbase = row0 + wr * 64 + mi * 16 + (lane >> 4) * 4;
            const size_t obase = (size_t)(n >> 8) * ((size_t)Mdim * 256) + (n & 255);
#pragma unroll
            for (int j = 0; j < 4; ++j)
                out[obase + (size_t)(rbase + j) * 256] = acc[mi][ni][j];
        }
}

extern "C" void kernel_launch(void* const* d_in, const int* in_sizes, int n_in,
                              void* d_out, int out_size, void* d_ws, size_t ws_size,
                              hipStream_t stream) {
    const float* X = (const float*)d_in[0];
    const float* W = (const float*)d_in[1];
    float* out     = (float*)d_out;
    if (ws_size >= WS_NEED) {
        f16* Xs = (f16*)d_ws;
        f16* Ws = Xs + XS_ELEMS;
        hipLaunchKernelGGL(convert_kernel, dim3((int)(XS_ELEMS / 8 / 256)), dim3(256),
                           0, stream, X, Xs);
        hipLaunchKernelGGL(convert_kernel, dim3((int)(WS_ELEMS / 8 / 256)), dim3(256),
                           0, stream, W, Ws);
        hipLaunchKernelGGL(gemm_a2a_kernel, dim3(NWG), dim3(512), 0, stream, Xs, Ws, out);
    } else {
        hipLaunchKernelGGL(gemm_a2a_f32_kernel, dim3(FNWG), dim3(256), 0, stream, X, W, out);
    }
}

// Round 22
// 333.545 us; speedup vs baseline: 1.6360x; 1.0492x over previous
//
#include <hip/hip_runtime.h>

// SPModel_6846177870356: y = x@W^T + all2all permute. M=28160, N=K=2048.
// Inputs FP32 (harness-upcast fp16), output FP32.
// Round 22 = R21 schedule (BK=32, triple-buffer, stagger-2, ONE vmcnt(4)
// gate per K-tile, reads pre-barrier, 2 barriers/phase, LGKM0+sched_barrier,
// setprio) with R11's VERIFIED 0-conflict row-pair LDS layout:
//   line = r>>1 (128B); byte_in_line = ((r&1)*64 + kc*2) ^ ((line&7)<<4)
// staged from LINEAR f16 globals via per-lane swizzled source
//   (u = (c&7)^(line&7); r = 2*line + (u>>2); k8 = u&3)   [R11-verified]
// R21's bit-6-crossing layout cost 2.16e7 bank-conflict cycles (~12%).
// XCD-bijective swizzle (T1), fused all2all f32 epilogue.

typedef _Float16 f16;
typedef _Float16 f16x2 __attribute__((ext_vector_type(2)));
typedef _Float16 f16x8 __attribute__((ext_vector_type(8)));
typedef float    f32x4 __attribute__((ext_vector_type(4)));

#define GPTR(p) ((const __attribute__((address_space(1))) void*)(p))
#define LPTR(p) ((__attribute__((address_space(3))) void*)(p))

constexpr int Mdim = 28160;   // 8*44*80
constexpr int Ndim = 2048;
constexpr int Kdim = 2048;
constexpr int BM = 256, BN = 256, BK = 32;
constexpr int NWG = (Mdim / BM) * (Ndim / BN);  // 880 (%8==0)
constexpr int NT  = Kdim / BK;                  // 64
constexpr size_t XS_ELEMS = (size_t)Mdim * Kdim;
constexpr size_t WS_ELEMS = (size_t)Ndim * Kdim;
constexpr size_t WS_NEED  = (XS_ELEMS + WS_ELEMS) * sizeof(f16);

__device__ __forceinline__ f16x8 pack8(const f32x4& lo, const f32x4& hi) {
    f16x2 p0 = __builtin_bit_cast(f16x2, __builtin_amdgcn_cvt_pkrtz(lo[0], lo[1]));
    f16x2 p1 = __builtin_bit_cast(f16x2, __builtin_amdgcn_cvt_pkrtz(lo[2], lo[3]));
    f16x2 p2 = __builtin_bit_cast(f16x2, __builtin_amdgcn_cvt_pkrtz(hi[0], hi[1]));
    f16x2 p3 = __builtin_bit_cast(f16x2, __builtin_amdgcn_cvt_pkrtz(hi[2], hi[3]));
    return (f16x8){p0[0], p0[1], p1[0], p1[1], p2[0], p2[1], p3[0], p3[1]};
}

// plain linear f32 -> f16 convert (R11-verified)
__global__ __launch_bounds__(256)
void convert_kernel(const float* __restrict__ src, f16* __restrict__ dst) {
    const size_t idx = ((size_t)blockIdx.x * 256 + threadIdx.x) * 8;
    f32x4 lo = *(const f32x4*)(src + idx);
    f32x4 hi = *(const f32x4*)(src + idx + 4);
    *(f16x8*)(dst + idx) = pack8(lo, hi);
}

// R11-verified row-pair swizzled read: 0 bank conflicts on hardware.
__device__ __forceinline__ f16x8 lds_frag(const f16* base, int r, int kc) {
    const int line = r >> 1;
    const int b    = (((r & 1) << 6) + (kc << 1)) ^ ((line & 7) << 4);
    return *(const f16x8*)((const char*)base + line * 128 + b);
}

__global__ __launch_bounds__(512, 2)
void gemm_a2a_kernel(const f16* __restrict__ Xs, const f16* __restrict__ Ws,
                     float* __restrict__ out) {
    __shared__ f16 sA[3][BM * BK];   // 16 KiB each (row-pair swizzled image)
    __shared__ f16 sB[3][BN * BK];   // total 96 KiB

    const int tid  = threadIdx.x;
    const int lane = tid & 63;
    const int wid  = tid >> 6;
    const int wm   = wid >> 2;          // 0..1 -> 128 M-rows
    const int wn   = wid & 3;           // 0..3 -> 64 N-cols

    const int cpx  = NWG >> 3;                       // XCD-bijective swizzle
    const int tile = (blockIdx.x & 7) * cpx + (blockIdx.x >> 3);
    const int bn   = tile & 7;
    const int bm   = tile >> 3;
    const int row0 = bm * BM;
    const int col0 = bn * BN;

    const int lr = lane & 15;
    const int kq = (lane >> 4) * 8;     // k-offset within BK=32

    f32x4 acc[8][4] = {};

    // Units (R21 geometry, unchanged dst bytes): A_u0 = tile rows
    // {0-63}u{128-191} (lines 0-31, 64-95); A_u1 = +4096B; B_u0 = rows 0-127;
    // B_u1 = rows 128-255. dst = wave-uniform base + lane*16 (G21 ok).
    const int betaA0 = (tid < 256) ? tid * 16 : 8192 + (tid - 256) * 16;
    const int betaA1 = betaA0 + 4096;
    const int betaB0 = tid * 16;
    const int betaB1 = 8192 + tid * 16;
    // Source offset for LDS byte beta (LINEAR globals, R11-verified mapping):
    // line=beta>>7; u=((beta>>4)&7)^(line&7); r=2*line+(u>>2); k8=u&3.
    auto srcoff = [&](int beta) {
        const int line = beta >> 7;
        const int u    = ((beta >> 4) & 7) ^ (line & 7);
        const int r    = 2 * line + (u >> 2);
        return (size_t)r * Kdim + (size_t)((u & 3) * 8);
    };
    const size_t sA0 = srcoff(betaA0), sA1 = srcoff(betaA1);
    const size_t sB0 = srcoff(betaB0), sB1 = srcoff(betaB1);
    const f16* Xb = Xs + (size_t)row0 * Kdim;
    const f16* Wb = Ws + (size_t)col0 * Kdim;

#define STAGE_A2(T, DA)                                                      \
    do {                                                                     \
        __builtin_amdgcn_global_load_lds(GPTR(Xb + sA0 + (T) * BK),          \
            LPTR((char*)(DA) + betaA0), 16, 0, 0);                           \
        __builtin_amdgcn_global_load_lds(GPTR(Xb + sA1 + (T) * BK),          \
            LPTR((char*)(DA) + betaA1), 16, 0, 0);                           \
    } while (0)
#define STAGE_B2(T, DB)                                                      \
    do {                                                                     \
        __builtin_amdgcn_global_load_lds(GPTR(Wb + sB0 + (T) * BK),          \
            LPTR((char*)(DB) + betaB0), 16, 0, 0);                           \
        __builtin_amdgcn_global_load_lds(GPTR(Wb + sB1 + (T) * BK),          \
            LPTR((char*)(DB) + betaB1), 16, 0, 0);                           \
    } while (0)

    f16x8 Af[4], Bf[4];
    auto readA = [&](const f16* base, int qm) {
#pragma unroll
        for (int f = 0; f < 4; ++f)
            Af[f] = lds_frag(base, wm * 128 + qm * 64 + f * 16 + lr, kq);
    };
    auto readB = [&](const f16* base) {
#pragma unroll
        for (int g = 0; g < 4; ++g)
            Bf[g] = lds_frag(base, wn * 64 + g * 16 + lr, kq);
    };

#define MFMA16(QM)                                                          \
    do {                                                                    \
        __builtin_amdgcn_s_setprio(1);                                      \
        _Pragma("unroll")                                                   \
        for (int f = 0; f < 4; ++f)                                         \
            _Pragma("unroll")                                               \
            for (int g = 0; g < 4; ++g)                                     \
                acc[(QM)*4 + f][g] =                                        \
                    __builtin_amdgcn_mfma_f32_16x16x32_f16(                 \
                        Af[f], Bf[g], acc[(QM)*4 + f][g], 0, 0, 0);         \
        __builtin_amdgcn_s_setprio(0);                                      \
    } while (0)

#define VM(N)   asm volatile("s_waitcnt vmcnt(" #N ")" ::: "memory")
#define BAR()   __builtin_amdgcn_s_barrier()
#define LGKM0() do { asm volatile("s_waitcnt lgkmcnt(0)" ::: "memory");     \
                     __builtin_amdgcn_sched_barrier(0); } while (0)

    f16 *cA = sA[0], *nA = sA[1], *gA = sA[2];
    f16 *cB = sB[0], *nB = sB[1], *gB = sB[2];

    // Prologue: stage tile 0 -> buf0, tile 1 -> buf1 (8 loads); certify t0.
    STAGE_A2(0, cA); STAGE_B2(0, cB);
    STAGE_A2(1, nA); STAGE_B2(1, nB);
    VM(4); BAR();                       // t0 certified; t1's 4 in flight

    for (int t = 0; t < NT - 2; ++t) {
        // p0: qm=0 — reads of tile t certified by previous tile's gate
        readA(cA, 0); readB(cB);
        STAGE_A2(t + 2, gA);
        BAR(); LGKM0();
        MFMA16(0);
        BAR();
        // p1: qm=1 (B held in regs)
        readA(cA, 1);
        STAGE_B2(t + 2, gB);
        VM(4); BAR(); LGKM0();          // drains tile t+1's 4 units (old)
        MFMA16(1);
        BAR();
        // rotate: cur <- next <- stage <- cur
        f16* tA = cA; cA = nA; nA = gA; gA = tA;
        f16* tB = cB; cB = nB; nB = gB; gB = tB;
    }
    // Peel t = NT-2: no staging; gate VM(0) certifies tile NT-1 (loads old).
    {
        readA(cA, 0); readB(cB);
        BAR(); LGKM0();
        MFMA16(0);
        BAR();
        readA(cA, 1);
        VM(0); BAR(); LGKM0();
        MFMA16(1);
        BAR();
        f16* tA = cA; cA = nA; nA = gA; gA = tA;
        f16* tB = cB; cB = nB; nB = gB; gB = tB;
    }
    // Peel t = NT-1: everything certified.
    {
        readA(cA, 0); readB(cB);
        BAR(); LGKM0();
        MFMA16(0);
        BAR();
        readA(cA, 1);
        LGKM0();
        MFMA16(1);
    }

    // Epilogue: C/D col=lane&15 (n), row=(lane>>4)*4+j (m); fused all2all:
    // out[(n>>8)*M*256 + m*256 + (n&255)], f32 stores.
    const int R0 = row0 + wm * 128;
    const int C0 = col0 + wn * 64;
#pragma unroll
    for (int mi = 0; mi < 8; ++mi)
#pragma unroll
        for (int ni = 0; ni < 4; ++ni) {
            const int n     = C0 + ni * 16 + lr;
            const int rbase = R0 + mi * 16 + (lane >> 4) * 4;
            const size_t obase = (size_t)(n >> 8) * ((size_t)Mdim * 256) + (n & 255);
#pragma unroll
            for (int j = 0; j < 4; ++j)
                out[obase + (size_t)(rbase + j) * 256] = acc[mi][ni][j];
        }
}

// ---- Fallback (R7-verified): direct-f32 reg-staged dbuf 128^2 kernel ----
constexpr int FBM = 128, FBK = 64;
constexpr int FNWG = (Mdim / FBM) * (Ndim / FBM);
__global__ __launch_bounds__(256)
void gemm_a2a_f32_kernel(const float* __restrict__ X, const float* __restrict__ W,
                         float* __restrict__ out) {
    __shared__ f16 sA[2][FBM * FBK];
    __shared__ f16 sB[2][FBM * FBK];
    const int tid  = threadIdx.x;
    const int lane = tid & 63;
    const int wid  = tid >> 6;
    const int wr   = wid >> 1;
    const int wc   = wid & 1;
    const int cpx  = FNWG >> 3;
    const int tile = (blockIdx.x & 7) * cpx + (blockIdx.x >> 3);
    const int bn   = tile & 15;
    const int bm   = tile >> 4;
    const int row0 = bm * FBM;
    const int col0 = bn * FBM;
    f32x4 acc[4][4] = {};
    f32x4 ra[8], rb[8];
    auto load_tile = [&](int t) {
#pragma unroll
        for (int i = 0; i < 4; ++i) {
            const int c8 = i * 256 + tid;
            const int r  = c8 >> 3;
            const int cc = (c8 & 7) * 8;
            const float* pa = X + (size_t)(row0 + r) * Kdim + t * FBK + cc;
            const float* pb = W + (size_t)(col0 + r) * Kdim + t * FBK + cc;
            ra[2*i] = *(const f32x4*)pa; ra[2*i+1] = *(const f32x4*)(pa + 4);
            rb[2*i] = *(const f32x4*)pb; rb[2*i+1] = *(const f32x4*)(pb + 4);
        }
    };
    int cur = 0;
    load_tile(0);
    for (int t = 0; t < Kdim / FBK; ++t) {
#pragma unroll
        for (int i = 0; i < 4; ++i) {
            const int c8 = i * 256 + tid;
            const int sb = (c8 * 16) ^ (((c8 >> 3) & 7) << 4);
            *(f16x8*)((char*)sA[cur] + sb) = pack8(ra[2*i], ra[2*i+1]);
            *(f16x8*)((char*)sB[cur] + sb) = pack8(rb[2*i], rb[2*i+1]);
        }
        if (t + 1 < Kdim / FBK) load_tile(t + 1);
        __syncthreads();
        const f16* Ab = sA[cur];
        const f16* Bb = sB[cur];
#pragma unroll
        for (int kk = 0; kk < FBK; kk += 32) {
            const int kc = kk + (lane >> 4) * 8;
            f16x8 af[4], bfr[4];
#pragma unroll
            for (int f = 0; f < 4; ++f) {
                const int rowA = wr * 64 + f * 16 + (lane & 15);
                af[f] = *(const f16x8*)((const char*)Ab + (((rowA * FBK + kc) * 2) ^ ((rowA & 7) << 4)));
                const int rowB = wc * 64 + f * 16 + (lane & 15);
                bfr[f] = *(const f16x8*)((const char*)Bb + (((rowB * FBK + kc) * 2) ^ ((rowB & 7) << 4)));
            }
#pragma unroll
            for (int mi = 0; mi < 4; ++mi)
#pragma unroll
                for (int ni = 0; ni < 4; ++ni)
                    acc[mi][ni] = __builtin_amdgcn_mfma_f32_16x16x32_f16(
                        af[mi], bfr[ni], acc[mi][ni], 0, 0, 0);
        }
        cur ^= 1;
    }
#pragma unroll
    for (int mi = 0; mi < 4; ++mi)
#pragma unroll
        for (int ni = 0; ni < 4; ++ni) {
            const int n     = col0 + wc * 64 + ni * 16 + (lane & 15);
            const int rbase = row0 + wr * 64 + mi * 16 + (lane >> 4) * 4;
            const size_t obase = (size_t)(n >> 8) * ((size_t)Mdim * 256) + (n & 255);
#pragma unroll
            for (int j = 0; j < 4; ++j)
                out[obase + (size_t)(rbase + j) * 256] = acc[mi][ni][j];
        }
}

extern "C" void kernel_launch(void* const* d_in, const int* in_sizes, int n_in,
                              void* d_out, int out_size, void* d_ws, size_t ws_size,
                              hipStream_t stream) {
    const float* X = (const float*)d_in[0];
    const float* W = (const float*)d_in[1];
    float* out     = (float*)d_out;
    if (ws_size >= WS_NEED) {
        f16* Xs = (f16*)d_ws;
        f16* Ws = Xs + XS_ELEMS;
        hipLaunchKernelGGL(convert_kernel, dim3((int)(XS_ELEMS / 8 / 256)), dim3(256),
                           0, stream, X, Xs);
        hipLaunchKernelGGL(convert_kernel, dim3((int)(WS_ELEMS / 8 / 256)), dim3(256),
                           0, stream, W, Ws);
        hipLaunchKernelGGL(gemm_a2a_kernel, dim3(NWG), dim3(512), 0, stream, Xs, Ws, out);
    } else {
        hipLaunchKernelGGL(gemm_a2a_f32_kernel, dim3(FNWG), dim3(256), 0, stream, X, W, out);
    }
}